// Round 8
// baseline (708.476 us; speedup 1.0000x reference)
//
#include <hip/hip_runtime.h>

#define NN 50000
#define NE 1600000
#define DD 128
#define NLAYERS 6
#define NG 8
#define BN_EPS 1e-5f

#define NBIN 196       // bins of 256 dst nodes
#define BINCAP 10240   // avg 8163/bin, sigma~90 -> +22 sigma headroom
#define EPB 8192       // edges per k_part block

typedef __bf16 bf16x8 __attribute__((ext_vector_type(8)));
typedef float f32x4 __attribute__((ext_vector_type(4)));

static __device__ __forceinline__ float bflo(unsigned u) {
    return __uint_as_float(u << 16);
}
static __device__ __forceinline__ float bfhi(unsigned u) {
    return __uint_as_float(u & 0xffff0000u);
}
static __device__ __forceinline__ unsigned pkbf(float a, float b) {
    __bf16 x = (__bf16)a, y = (__bf16)b;
    return (unsigned)*(unsigned short*)&x | ((unsigned)*(unsigned short*)&y << 16);
}

// ---------------- CSR build: 2-pass bin partition (R6-proven) ----------------

__global__ __launch_bounds__(1024) void k_part(const int* __restrict__ src,
                                               const int* __restrict__ dst,
                                               int* __restrict__ bincur,
                                               int2* __restrict__ scratch) {
    __shared__ int lh[NBIN], lbase[NBIN];
    const int t = threadIdx.x;
    const int e0 = blockIdx.x * EPB;
    int s8[8], d8[8];
#pragma unroll
    for (int j = 0; j < 8; ++j) {
        int e = e0 + j * 1024 + t;
        if (e < NE) { s8[j] = src[e]; d8[j] = dst[e]; }
        else d8[j] = -1;
    }
    if (t < NBIN) lh[t] = 0;
    __syncthreads();
#pragma unroll
    for (int j = 0; j < 8; ++j)
        if (d8[j] >= 0) atomicAdd(&lh[d8[j] >> 8], 1);
    __syncthreads();
    if (t < NBIN) {
        int c = lh[t];
        lbase[t] = c ? atomicAdd(&bincur[t], c) : 0;
        lh[t] = 0;
    }
    __syncthreads();
#pragma unroll
    for (int j = 0; j < 8; ++j)
        if (d8[j] >= 0) {
            int b = d8[j] >> 8;
            int p = lbase[b] + atomicAdd(&lh[b], 1);
            if (p < BINCAP) scratch[(size_t)b * BINCAP + p] = make_int2(s8[j], d8[j]);
        }
}

__global__ __launch_bounds__(256) void k_binscan(const int* __restrict__ bincur,
                                                 int* __restrict__ binbase,
                                                 int* __restrict__ off) {
    __shared__ int sc[256];
    int t = threadIdx.x;
    sc[t] = (t < NBIN) ? bincur[t] : 0;
    __syncthreads();
    for (int d = 1; d < 256; d <<= 1) {
        int v = (t >= d) ? sc[t - d] : 0;
        __syncthreads();
        sc[t] += v;
        __syncthreads();
    }
    binbase[t] = (t == 0) ? 0 : sc[t - 1];
    if (t == 0) off[NN] = NE;
}

__global__ __launch_bounds__(1024) void k_csr(const int* __restrict__ bincur,
                                              const int* __restrict__ binbase,
                                              const int2* __restrict__ scratch,
                                              int* __restrict__ off,
                                              int* __restrict__ csr,
                                              float* __restrict__ degf) {
    __shared__ int nh[256], no[256], ncur[256];
    const int t = threadIdx.x;
    const int b = blockIdx.x;
    int cnt = bincur[b]; if (cnt > BINCAP) cnt = BINCAP;
    const int base = binbase[b];
    if (t < 256) nh[t] = 0;
    __syncthreads();
    for (int i = t; i < cnt; i += 1024) {
        int2 p = scratch[(size_t)b * BINCAP + i];
        atomicAdd(&nh[p.y & 255], 1);
    }
    __syncthreads();
    if (t < 256) no[t] = nh[t];
    __syncthreads();
    for (int d = 1; d < 256; d <<= 1) {
        int v = 0;
        if (t < 256 && t >= d) v = no[t - d];
        __syncthreads();
        if (t < 256) no[t] += v;
        __syncthreads();
    }
    if (t < 256) {
        int excl = (t == 0) ? 0 : no[t - 1];
        ncur[t] = excl;
        int n = b * 256 + t;
        if (n < NN) {
            off[n] = base + excl;
            degf[n] = (float)nh[t];
        }
    }
    __syncthreads();
    for (int i = t; i < cnt; i += 1024) {
        int2 p = scratch[(size_t)b * BINCAP + i];
        int pos = atomicAdd(&ncur[p.y & 255], 1);
        csr[base + pos] = p.x;
    }
}

__global__ void k_init_st(float* __restrict__ st) {
    int t = threadIdx.x;
    st[t] = (t < DD) ? 1.f : 0.f;
}

// ---------------- x -> bf16 copy ----------------

__global__ __launch_bounds__(256) void k_xtobf(const float* __restrict__ x,
                                               unsigned short* __restrict__ xb) {
    size_t i = (size_t)(blockIdx.x * 256 + threadIdx.x) * 8;
    float4 a = *(const float4*)(x + i);
    float4 b = *(const float4*)(x + i + 4);
    uint4 o;
    o.x = pkbf(a.x, a.y); o.y = pkbf(a.z, a.w);
    o.z = pkbf(b.x, b.y); o.w = pkbf(b.z, b.w);
    *(uint4*)(xb + i) = o;
}

// ---------------- per-layer weight prep ----------------
// wfrag[pass][hl][ks][ct][lane][8] = hi/lo of s[k]*W[k][col],
//   col = ct*16 + (lane&15), k = ks*32 + (lane>>4)*8 + j  (exact MFMA frag layout)
// biast[0..127]  = brel + t @ Wroot
// biast[128..255]= t @ Wrel

__global__ __launch_bounds__(256) void k_prep(const float* __restrict__ Wrel,
                                              const float* __restrict__ Wroot,
                                              const float* __restrict__ brel,
                                              const float* __restrict__ st,
                                              __bf16* __restrict__ wfrag,
                                              float* __restrict__ biast) {
    int b = blockIdx.x;
    if (b < 16) {
        int gid = b * 256 + threadIdx.x;       // 4096 tasks
        int pass = gid >> 11;
        int r = gid & 2047;
        int ks = r >> 9;
        int r2 = r & 511;
        int ct = r2 >> 6;
        int lane = r2 & 63;
        int col = ct * 16 + (lane & 15);
        int kb = ks * 32 + (lane >> 4) * 8;
        const float* W = pass ? Wroot : Wrel;
        bf16x8 vh, vl;
#pragma unroll
        for (int j = 0; j < 8; ++j) {
            int k = kb + j;
            float v = st[k] * W[(size_t)k * DD + col];
            __bf16 hb = (__bf16)v;
            vh[j] = hb;
            vl[j] = (__bf16)(v - (float)hb);
        }
        size_t oh = (((size_t)(pass * 2 + 0) * 4 + ks) * 8 + ct) * 512 + lane * 8;
        *(bf16x8*)(wfrag + oh) = vh;
        *(bf16x8*)(wfrag + oh + 16384) = vl;   // hl=1 stride = 4*8*512
    } else {
        int t = threadIdx.x;
        int col = t & 127;
        bool isT = t >= 128;
        const float* W = isT ? Wrel : Wroot;
        float s = 0.f;
        for (int k = 0; k < DD; ++k)
            s = fmaf(st[DD + k], W[(size_t)k * DD + col], s);
        if (isT) biast[128 + col] = s;
        else biast[col] = brel[col] + s;
    }
}

// ---------------- aggregation: raw bf16 row sums, one wave per dst node ----------

#define ACC8(v) {                                              \
    a0 += bflo(v.x); a1 += bfhi(v.x);                          \
    a2 += bflo(v.y); a3 += bfhi(v.y);                          \
    a4 += bflo(v.z); a5 += bfhi(v.z);                          \
    a6 += bflo(v.w); a7 += bfhi(v.w); }

__global__ __launch_bounds__(256) void k_agg(const unsigned short* __restrict__ hb,
                                             const int* __restrict__ off,
                                             const int* __restrict__ csr,
                                             float* __restrict__ agg) {
    int w = (blockIdx.x * blockDim.x + threadIdx.x) >> 6;
    int lane = threadIdx.x & 63;
    if (w >= NN) return;
    int lo = off[w], hi = off[w + 1];
    const int q = lane >> 4;
    const int colo = lane & 15;
    const uint4* hp = (const uint4*)hb;
    float a0 = 0.f, a1 = 0.f, a2 = 0.f, a3 = 0.f, a4 = 0.f, a5 = 0.f, a6 = 0.f, a7 = 0.f;
    int e = lo;
    for (; e + 8 <= hi; e += 8) {
        int s0 = csr[e + q];
        int s1 = csr[e + 4 + q];
        uint4 v0 = hp[(size_t)s0 * 16 + colo];
        uint4 v1 = hp[(size_t)s1 * 16 + colo];
        ACC8(v0);
        ACC8(v1);
    }
    for (; e + 4 <= hi; e += 4) {
        int s = csr[e + q];
        uint4 v = hp[(size_t)s * 16 + colo];
        ACC8(v);
    }
    a0 += __shfl_xor(a0, 16); a1 += __shfl_xor(a1, 16);
    a2 += __shfl_xor(a2, 16); a3 += __shfl_xor(a3, 16);
    a4 += __shfl_xor(a4, 16); a5 += __shfl_xor(a5, 16);
    a6 += __shfl_xor(a6, 16); a7 += __shfl_xor(a7, 16);
    a0 += __shfl_xor(a0, 32); a1 += __shfl_xor(a1, 32);
    a2 += __shfl_xor(a2, 32); a3 += __shfl_xor(a3, 32);
    a4 += __shfl_xor(a4, 32); a5 += __shfl_xor(a5, 32);
    a6 += __shfl_xor(a6, 32); a7 += __shfl_xor(a7, 32);
    for (; e < hi; ++e) {
        int s = csr[e];
        uint4 v = hp[(size_t)s * 16 + colo];
        ACC8(v);
    }
    if (lane < 16) {
        float4 oA = make_float4(a0, a1, a2, a3);
        float4 oB = make_float4(a4, a5, a6, a7);
        ((float4*)agg)[(size_t)w * 32 + colo * 2] = oA;
        ((float4*)agg)[(size_t)w * 32 + colo * 2 + 1] = oB;
    }
}

// ---------------- LDS-free MFMA GEMM + bias + relu + stats ----------------
// Block = 64 rows (4 waves x 16 rows) x 128 cols. No staging LDS, no main-loop
// barriers. A-frags loaded per-lane from global; B-frags coalesced from wfrag.
// out = relu(rawagg @ W'rel + h @ W'root + biast + deg * trel), stored bf16.

__global__ __launch_bounds__(256, 3) void k_gemm(const float* __restrict__ agg,
                                                 const unsigned short* __restrict__ hb_in,
                                                 const __bf16* __restrict__ wfrag,
                                                 const float* __restrict__ biast,
                                                 const float* __restrict__ degf,
                                                 unsigned short* __restrict__ hb_out,
                                                 float* __restrict__ stats) {
    __shared__ float sb[4][128], qb[4][128];
    const int tid = threadIdx.x;
    const int w = tid >> 6, lane = tid & 63;
    const int lrow = lane & 15, lk = lane >> 4;
    const int r0 = blockIdx.x * 64 + w * 16;
    const int n_a = r0 + lrow;          // row this lane loads A for

    f32x4 acc[8];
#pragma unroll
    for (int ct = 0; ct < 8; ++ct) acc[ct] = (f32x4){0.f, 0.f, 0.f, 0.f};

#pragma unroll
    for (int pass = 0; pass < 2; ++pass) {
#pragma unroll
        for (int ks = 0; ks < 4; ++ks) {
            bf16x8 ah, al;
            if (pass == 0) {
                float v[8];
                if (n_a < NN) {
                    const float* ap = agg + (size_t)n_a * DD + ks * 32 + lk * 8;
                    float4 a = *(const float4*)ap;
                    float4 b = *(const float4*)(ap + 4);
                    v[0] = a.x; v[1] = a.y; v[2] = a.z; v[3] = a.w;
                    v[4] = b.x; v[5] = b.y; v[6] = b.z; v[7] = b.w;
                } else {
#pragma unroll
                    for (int j = 0; j < 8; ++j) v[j] = 0.f;
                }
#pragma unroll
                for (int j = 0; j < 8; ++j) {
                    __bf16 hv = (__bf16)v[j];
                    ah[j] = hv;
                    al[j] = (__bf16)(v[j] - (float)hv);
                }
            } else {
                if (n_a < NN) {
                    ah = *(const bf16x8*)(hb_in + (size_t)n_a * DD + ks * 32 + lk * 8);
                } else {
#pragma unroll
                    for (int j = 0; j < 8; ++j) ah[j] = (__bf16)0.f;
                }
            }
            const __bf16* bh_base = wfrag + ((size_t)(pass * 2 + 0) * 4 + ks) * 4096 + lane * 8;
            const __bf16* bl_base = wfrag + ((size_t)(pass * 2 + 1) * 4 + ks) * 4096 + lane * 8;
#pragma unroll
            for (int ct = 0; ct < 8; ++ct) {
                bf16x8 bh = *(const bf16x8*)(bh_base + ct * 512);
                bf16x8 bl = *(const bf16x8*)(bl_base + ct * 512);
                acc[ct] = __builtin_amdgcn_mfma_f32_16x16x32_bf16(ah, bh, acc[ct], 0, 0, 0);
                if (pass == 0)
                    acc[ct] = __builtin_amdgcn_mfma_f32_16x16x32_bf16(al, bh, acc[ct], 0, 0, 0);
                acc[ct] = __builtin_amdgcn_mfma_f32_16x16x32_bf16(ah, bl, acc[ct], 0, 0, 0);
            }
        }
    }

    // epilogue: D layout col = lane&15, row = (lane>>4)*4 + reg
    float cs[8], cq[8];
#pragma unroll
    for (int ct = 0; ct < 8; ++ct) { cs[ct] = 0.f; cq[ct] = 0.f; }
#pragma unroll
    for (int ct = 0; ct < 8; ++ct) {
        int col = ct * 16 + lrow;
        float bt = biast[col];
        float tr = biast[128 + col];
#pragma unroll
        for (int q = 0; q < 4; ++q) {
            int n = r0 + lk * 4 + q;
            if (n < NN) {
                float o = fmaxf(acc[ct][q] + bt + degf[n] * tr, 0.f);
                __bf16 ob = (__bf16)o;
                hb_out[(size_t)n * DD + col] = *(unsigned short*)&ob;
                cs[ct] += o;
                cq[ct] += o * o;
            }
        }
    }
#pragma unroll
    for (int ct = 0; ct < 8; ++ct) {
        cs[ct] += __shfl_xor(cs[ct], 16);
        cs[ct] += __shfl_xor(cs[ct], 32);
        cq[ct] += __shfl_xor(cq[ct], 16);
        cq[ct] += __shfl_xor(cq[ct], 32);
    }
    if (lane < 16) {
#pragma unroll
        for (int ct = 0; ct < 8; ++ct) {
            sb[w][ct * 16 + lrow] = cs[ct];
            qb[w][ct * 16 + lrow] = cq[ct];
        }
    }
    __syncthreads();
    if (tid < 128) {
        float s = sb[0][tid] + sb[1][tid] + sb[2][tid] + sb[3][tid];
        atomicAdd(&stats[tid], s);
    } else {
        int c2 = tid - 128;
        float s = qb[0][c2] + qb[1][c2] + qb[2][c2] + qb[3][c2];
        atomicAdd(&stats[DD + c2], s);
    }
}

__global__ void k_bn(float* __restrict__ stats, const float* __restrict__ gamma,
                     const float* __restrict__ beta, float* __restrict__ st) {
    int c = threadIdx.x;
    float mean = stats[c] * (1.0f / NN);
    float var = stats[DD + c] * (1.0f / NN) - mean * mean;
    float s = gamma[c] / sqrtf(var + BN_EPS);
    st[c] = s;
    st[DD + c] = beta[c] - mean * s;
    stats[c] = 0.f;
    stats[DD + c] = 0.f;
}

// ---------------- pooling (bf16 input) ----------------

#define POOL_BLOCKS 128

__global__ __launch_bounds__(256) void k_pool(const unsigned short* __restrict__ hb,
                                              const int* __restrict__ batch,
                                              float* __restrict__ pooled,
                                              float* __restrict__ counts) {
    const int c = threadIdx.x & 127;
    const int half = threadIdx.x >> 7;
    const int chunk = (NN + POOL_BLOCKS - 1) / POOL_BLOCKS;
    int lo = blockIdx.x * chunk;
    int hi = lo + chunk; if (hi > NN) hi = NN;
    float acc = 0.f;
    int cur = -1, cnt = 0;
    for (int n = lo + half; n < hi; n += 2) {
        int g = batch[n];
        float v = __uint_as_float((unsigned)hb[(size_t)n * DD + c] << 16);
        if (g != cur) {
            if (cur >= 0) {
                atomicAdd(&pooled[cur * DD + c], acc);
                if (c == 0) atomicAdd(&counts[cur], (float)cnt);
            }
            cur = g; acc = 0.f; cnt = 0;
        }
        acc += v; cnt++;
    }
    if (cur >= 0) {
        atomicAdd(&pooled[cur * DD + c], acc);
        if (c == 0) atomicAdd(&counts[cur], (float)cnt);
    }
}

// ---------------- head ----------------

__global__ __launch_bounds__(1024) void k_head(const float* __restrict__ pooled,
                                               const float* __restrict__ counts,
                                               const float* __restrict__ st,
                                               const float* __restrict__ dw,
                                               const float* __restrict__ db,
                                               const float* __restrict__ muw,
                                               const float* __restrict__ mub,
                                               float* __restrict__ out) {
    __shared__ float pm[NG][DD];
    __shared__ float zs[NG][DD];
    int t = threadIdx.x;
    int g = t >> 7, c = t & 127;
    float cntg = counts[g];
    pm[g][c] = fmaf(st[c], pooled[g * DD + c], st[DD + c] * cntg) / fmaxf(cntg, 1.0f);
    __syncthreads();
    float acc = 0.f;
    for (int k = 0; k < DD; ++k)
        acc = fmaf(pm[g][k], dw[k * DD + c], acc);
    float z = fmaxf(acc + db[c], 0.f);
    zs[g][c] = z * muw[c];
    __syncthreads();
    if (c == 0) {
        float s = 0.f;
        for (int k = 0; k < DD; ++k) s += zs[g][k];
        out[g] = s + mub[0];
    }
}

// ---------------- host ----------------

extern "C" void kernel_launch(void* const* d_in, const int* in_sizes, int n_in,
                              void* d_out, int out_size, void* d_ws, size_t ws_size,
                              hipStream_t stream) {
    const float* x      = (const float*)d_in[0];
    const int*   ei     = (const int*)d_in[1];
    const int*   batch  = (const int*)d_in[2];
    const float* W_rel  = (const float*)d_in[3];
    const float* b_rel  = (const float*)d_in[4];
    const float* W_root = (const float*)d_in[5];
    const float* gamma  = (const float*)d_in[6];
    const float* beta   = (const float*)d_in[7];
    const float* dw     = (const float*)d_in[8];
    const float* db     = (const float*)d_in[9];
    const float* muw    = (const float*)d_in[10];
    const float* mub    = (const float*)d_in[11];
    float* out = (float*)d_out;

    char* w = (char*)d_ws;
    auto alloc = [&](size_t bytes) {
        char* p = w;
        w += (bytes + 255) & ~(size_t)255;
        return p;
    };
    int*    off     = (int*)alloc((size_t)(NN + 1) * 4);
    int*    csr     = (int*)alloc((size_t)NE * 4);
    float*  aggb    = (float*)alloc((size_t)NN * DD * 4);  // doubles as partition scratch
    unsigned short* hbA = (unsigned short*)alloc((size_t)NN * DD * 2);
    unsigned short* hbB = (unsigned short*)alloc((size_t)NN * DD * 2);
    float*  degf    = (float*)alloc((size_t)NN * 4);
    float*  stats   = (float*)alloc(2 * DD * 4);
    float*  st      = (float*)alloc(2 * DD * 4);
    float*  biast   = (float*)alloc(2 * DD * 4);
    float*  pooled  = (float*)alloc(NG * DD * 4);
    float*  counts  = (float*)alloc(NG * 4);
    int*    bincur  = (int*)alloc(256 * 4);
    int*    binbase = (int*)alloc(256 * 4);
    __bf16* wfrag   = (__bf16*)alloc((size_t)65536 * 2);   // 128 KB, rewritten per layer

    const int* src = ei;
    const int* dst = ei + NE;
    int2* scratch = (int2*)aggb;  // NBIN*BINCAP*8 = 16.06 MB <= 25.6 MB

    hipMemsetAsync(bincur, 0, 256 * 4, stream);
    hipMemsetAsync(stats, 0, 2 * DD * 4, stream);
    k_part<<<(NE + EPB - 1) / EPB, 1024, 0, stream>>>(src, dst, bincur, scratch);
    k_binscan<<<1, 256, 0, stream>>>(bincur, binbase, off);
    k_csr<<<NBIN, 1024, 0, stream>>>(bincur, binbase, scratch, off, csr, degf);
    k_init_st<<<1, 256, 0, stream>>>(st);
    k_xtobf<<<(NN * DD / 8 + 255) / 256, 256, 0, stream>>>(x, hbA);

    const unsigned short* hcur = hbA;
    unsigned short* bufs[2] = {hbB, hbA};
    for (int i = 0; i < NLAYERS; ++i) {
        unsigned short* hnext = bufs[i & 1];
        k_prep<<<17, 256, 0, stream>>>(W_rel + (size_t)i * DD * DD,
                                       W_root + (size_t)i * DD * DD,
                                       b_rel + (size_t)i * DD, st, wfrag, biast);
        k_agg<<<(NN * 64 + 255) / 256, 256, 0, stream>>>(hcur, off, csr, aggb);
        k_gemm<<<(NN + 63) / 64, 256, 0, stream>>>(aggb, hcur, wfrag, biast, degf,
                                                   hnext, stats);
        k_bn<<<1, 128, 0, stream>>>(stats, gamma + (size_t)i * DD, beta + (size_t)i * DD, st);
        hcur = hnext;
    }
    hipMemsetAsync(pooled, 0, (size_t)NG * DD * 4, stream);
    hipMemsetAsync(counts, 0, (size_t)NG * 4, stream);
    k_pool<<<POOL_BLOCKS, 256, 0, stream>>>(hcur, batch, pooled, counts);
    k_head<<<1, 1024, 0, stream>>>(pooled, counts, st, dw, db, muw, mub, out);
}

// Round 9
// 698.554 us; speedup vs baseline: 1.0142x; 1.0142x over previous
//
#include <hip/hip_runtime.h>

#define NN 50000
#define NE 1600000
#define DD 128
#define NLAYERS 6
#define NG 8
#define BN_EPS 1e-5f

#define NBIN 196       // bins of 256 dst nodes
#define BINCAP 10240   // avg 8163/bin, sigma~90 -> +22 sigma headroom
#define EPB 8192       // edges per k_part block
#define PB 128         // pool partial blocks

typedef __bf16 bf16x8 __attribute__((ext_vector_type(8)));
typedef float f32x4 __attribute__((ext_vector_type(4)));

static __device__ __forceinline__ float bflo(unsigned u) {
    return __uint_as_float(u << 16);
}
static __device__ __forceinline__ float bfhi(unsigned u) {
    return __uint_as_float(u & 0xffff0000u);
}
static __device__ __forceinline__ unsigned pkbf(float a, float b) {
    __bf16 x = (__bf16)a, y = (__bf16)b;
    return (unsigned)*(unsigned short*)&x | ((unsigned)*(unsigned short*)&y << 16);
}

// ---------------- CSR build: 2-pass bin partition (R6-proven) ----------------

__global__ __launch_bounds__(1024) void k_part(const int* __restrict__ src,
                                               const int* __restrict__ dst,
                                               int* __restrict__ bincur,
                                               int2* __restrict__ scratch) {
    __shared__ int lh[NBIN], lbase[NBIN];
    const int t = threadIdx.x;
    const int e0 = blockIdx.x * EPB;
    int s8[8], d8[8];
#pragma unroll
    for (int j = 0; j < 8; ++j) {
        int e = e0 + j * 1024 + t;
        if (e < NE) { s8[j] = src[e]; d8[j] = dst[e]; }
        else d8[j] = -1;
    }
    if (t < NBIN) lh[t] = 0;
    __syncthreads();
#pragma unroll
    for (int j = 0; j < 8; ++j)
        if (d8[j] >= 0) atomicAdd(&lh[d8[j] >> 8], 1);
    __syncthreads();
    if (t < NBIN) {
        int c = lh[t];
        lbase[t] = c ? atomicAdd(&bincur[t], c) : 0;
        lh[t] = 0;
    }
    __syncthreads();
#pragma unroll
    for (int j = 0; j < 8; ++j)
        if (d8[j] >= 0) {
            int b = d8[j] >> 8;
            int p = lbase[b] + atomicAdd(&lh[b], 1);
            if (p < BINCAP) scratch[(size_t)b * BINCAP + p] = make_int2(s8[j], d8[j]);
        }
}

__global__ __launch_bounds__(256) void k_binscan(const int* __restrict__ bincur,
                                                 int* __restrict__ binbase,
                                                 int* __restrict__ off) {
    __shared__ int sc[256];
    int t = threadIdx.x;
    sc[t] = (t < NBIN) ? bincur[t] : 0;
    __syncthreads();
    for (int d = 1; d < 256; d <<= 1) {
        int v = (t >= d) ? sc[t - d] : 0;
        __syncthreads();
        sc[t] += v;
        __syncthreads();
    }
    binbase[t] = (t == 0) ? 0 : sc[t - 1];
    if (t == 0) off[NN] = NE;
}

__global__ __launch_bounds__(1024) void k_csr(const int* __restrict__ bincur,
                                              const int* __restrict__ binbase,
                                              const int2* __restrict__ scratch,
                                              int* __restrict__ off,
                                              int* __restrict__ csr,
                                              float* __restrict__ degf) {
    __shared__ int nh[256], no[256], ncur[256];
    const int t = threadIdx.x;
    const int b = blockIdx.x;
    int cnt = bincur[b]; if (cnt > BINCAP) cnt = BINCAP;
    const int base = binbase[b];
    if (t < 256) nh[t] = 0;
    __syncthreads();
    for (int i = t; i < cnt; i += 1024) {
        int2 p = scratch[(size_t)b * BINCAP + i];
        atomicAdd(&nh[p.y & 255], 1);
    }
    __syncthreads();
    if (t < 256) no[t] = nh[t];
    __syncthreads();
    for (int d = 1; d < 256; d <<= 1) {
        int v = 0;
        if (t < 256 && t >= d) v = no[t - d];
        __syncthreads();
        if (t < 256) no[t] += v;
        __syncthreads();
    }
    if (t < 256) {
        int excl = (t == 0) ? 0 : no[t - 1];
        ncur[t] = excl;
        int n = b * 256 + t;
        if (n < NN) {
            off[n] = base + excl;
            degf[n] = (float)nh[t];
        }
    }
    __syncthreads();
    for (int i = t; i < cnt; i += 1024) {
        int2 p = scratch[(size_t)b * BINCAP + i];
        int pos = atomicAdd(&ncur[p.y & 255], 1);
        csr[base + pos] = p.x;
    }
}

// ---------------- x -> bf16 copy ----------------

__global__ __launch_bounds__(256) void k_xtobf(const float* __restrict__ x,
                                               unsigned short* __restrict__ xb) {
    size_t i = (size_t)(blockIdx.x * 256 + threadIdx.x) * 8;
    float4 a = *(const float4*)(x + i);
    float4 b = *(const float4*)(x + i + 4);
    uint4 o;
    o.x = pkbf(a.x, a.y); o.y = pkbf(a.z, a.w);
    o.z = pkbf(b.x, b.y); o.w = pkbf(b.z, b.w);
    *(uint4*)(xb + i) = o;
}

// ---------------- per-layer weight prep (BN fold inline from stats) ----------
// s[k] = gamma[k]*rsqrt(var[k]+eps), t[k] = beta[k]-mean[k]*s[k]  (prev layer BN)
// wfrag[pass][hl][ks][ct][lane][8] = hi/lo of s[k]*W[k][col]
// biast[0..127]  = brel + t @ Wroot ; biast[128..255] = t @ Wrel

__global__ __launch_bounds__(256) void k_prep(const float* __restrict__ Wrel,
                                              const float* __restrict__ Wroot,
                                              const float* __restrict__ brel,
                                              const float* __restrict__ gammaP,
                                              const float* __restrict__ betaP,
                                              const float* __restrict__ statsP,
                                              int first,
                                              __bf16* __restrict__ wfrag,
                                              float* __restrict__ biast) {
    int b = blockIdx.x;
    if (b < 16) {
        int gid = b * 256 + threadIdx.x;       // 4096 tasks
        int pass = gid >> 11;
        int r = gid & 2047;
        int ks = r >> 9;
        int r2 = r & 511;
        int ct = r2 >> 6;
        int lane = r2 & 63;
        int col = ct * 16 + (lane & 15);
        int kb = ks * 32 + (lane >> 4) * 8;
        const float* W = pass ? Wroot : Wrel;
        bf16x8 vh, vl;
#pragma unroll
        for (int j = 0; j < 8; ++j) {
            int k = kb + j;
            float s = 1.f;
            if (!first) {
                float m = statsP[k] * (1.0f / NN);
                float var = statsP[DD + k] * (1.0f / NN) - m * m;
                s = gammaP[k] * rsqrtf(var + BN_EPS);
            }
            float v = s * W[(size_t)k * DD + col];
            __bf16 hb = (__bf16)v;
            vh[j] = hb;
            vl[j] = (__bf16)(v - (float)hb);
        }
        size_t oh = (((size_t)(pass * 2 + 0) * 4 + ks) * 8 + ct) * 512 + lane * 8;
        *(bf16x8*)(wfrag + oh) = vh;
        *(bf16x8*)(wfrag + oh + 16384) = vl;
    } else {
        int t = threadIdx.x;
        int col = t & 127;
        bool isT = t >= 128;
        const float* W = isT ? Wrel : Wroot;
        float acc = 0.f;
        if (!first) {
            for (int k = 0; k < DD; ++k) {
                float m = statsP[k] * (1.0f / NN);
                float var = statsP[DD + k] * (1.0f / NN) - m * m;
                float s = gammaP[k] * rsqrtf(var + BN_EPS);
                float tv = betaP[k] - m * s;
                acc = fmaf(tv, W[(size_t)k * DD + col], acc);
            }
        }
        if (isT) biast[128 + col] = acc;
        else biast[col] = brel[col] + acc;
    }
}

// ---------------- aggregation: raw bf16 row sums, one wave per dst node ----------

#define ACC8(v) {                                              \
    a0 += bflo(v.x); a1 += bfhi(v.x);                          \
    a2 += bflo(v.y); a3 += bfhi(v.y);                          \
    a4 += bflo(v.z); a5 += bfhi(v.z);                          \
    a6 += bflo(v.w); a7 += bfhi(v.w); }

__global__ __launch_bounds__(256) void k_agg(const unsigned short* __restrict__ hb,
                                             const int* __restrict__ off,
                                             const int* __restrict__ csr,
                                             float* __restrict__ agg) {
    int w = (blockIdx.x * blockDim.x + threadIdx.x) >> 6;
    int lane = threadIdx.x & 63;
    if (w >= NN) return;
    int lo = off[w], hi = off[w + 1];
    const int q = lane >> 4;
    const int colo = lane & 15;
    const uint4* hp = (const uint4*)hb;
    float a0 = 0.f, a1 = 0.f, a2 = 0.f, a3 = 0.f, a4 = 0.f, a5 = 0.f, a6 = 0.f, a7 = 0.f;
    int e = lo;
    for (; e + 16 <= hi; e += 16) {
        int s0 = csr[e + q];
        int s1 = csr[e + 4 + q];
        int s2 = csr[e + 8 + q];
        int s3 = csr[e + 12 + q];
        uint4 v0 = hp[(size_t)s0 * 16 + colo];
        uint4 v1 = hp[(size_t)s1 * 16 + colo];
        uint4 v2 = hp[(size_t)s2 * 16 + colo];
        uint4 v3 = hp[(size_t)s3 * 16 + colo];
        ACC8(v0);
        ACC8(v1);
        ACC8(v2);
        ACC8(v3);
    }
    for (; e + 4 <= hi; e += 4) {
        int s = csr[e + q];
        uint4 v = hp[(size_t)s * 16 + colo];
        ACC8(v);
    }
    a0 += __shfl_xor(a0, 16); a1 += __shfl_xor(a1, 16);
    a2 += __shfl_xor(a2, 16); a3 += __shfl_xor(a3, 16);
    a4 += __shfl_xor(a4, 16); a5 += __shfl_xor(a5, 16);
    a6 += __shfl_xor(a6, 16); a7 += __shfl_xor(a7, 16);
    a0 += __shfl_xor(a0, 32); a1 += __shfl_xor(a1, 32);
    a2 += __shfl_xor(a2, 32); a3 += __shfl_xor(a3, 32);
    a4 += __shfl_xor(a4, 32); a5 += __shfl_xor(a5, 32);
    a6 += __shfl_xor(a6, 32); a7 += __shfl_xor(a7, 32);
    for (; e < hi; ++e) {
        int s = csr[e];
        uint4 v = hp[(size_t)s * 16 + colo];
        ACC8(v);
    }
    if (lane < 16) {
        float4 oA = make_float4(a0, a1, a2, a3);
        float4 oB = make_float4(a4, a5, a6, a7);
        ((float4*)agg)[(size_t)w * 32 + colo * 2] = oA;
        ((float4*)agg)[(size_t)w * 32 + colo * 2 + 1] = oB;
    }
}

// ---------------- LDS-free MFMA GEMM + bias + relu + stats (R8-proven) ---------

__global__ __launch_bounds__(256, 3) void k_gemm(const float* __restrict__ agg,
                                                 const unsigned short* __restrict__ hb_in,
                                                 const __bf16* __restrict__ wfrag,
                                                 const float* __restrict__ biast,
                                                 const float* __restrict__ degf,
                                                 unsigned short* __restrict__ hb_out,
                                                 float* __restrict__ stats) {
    __shared__ float sb[4][128], qb[4][128];
    const int tid = threadIdx.x;
    const int w = tid >> 6, lane = tid & 63;
    const int lrow = lane & 15, lk = lane >> 4;
    const int r0 = blockIdx.x * 64 + w * 16;
    const int n_a = r0 + lrow;

    f32x4 acc[8];
#pragma unroll
    for (int ct = 0; ct < 8; ++ct) acc[ct] = (f32x4){0.f, 0.f, 0.f, 0.f};

#pragma unroll
    for (int pass = 0; pass < 2; ++pass) {
#pragma unroll
        for (int ks = 0; ks < 4; ++ks) {
            bf16x8 ah, al;
            if (pass == 0) {
                float v[8];
                if (n_a < NN) {
                    const float* ap = agg + (size_t)n_a * DD + ks * 32 + lk * 8;
                    float4 a = *(const float4*)ap;
                    float4 b = *(const float4*)(ap + 4);
                    v[0] = a.x; v[1] = a.y; v[2] = a.z; v[3] = a.w;
                    v[4] = b.x; v[5] = b.y; v[6] = b.z; v[7] = b.w;
                } else {
#pragma unroll
                    for (int j = 0; j < 8; ++j) v[j] = 0.f;
                }
#pragma unroll
                for (int j = 0; j < 8; ++j) {
                    __bf16 hv = (__bf16)v[j];
                    ah[j] = hv;
                    al[j] = (__bf16)(v[j] - (float)hv);
                }
            } else {
                if (n_a < NN) {
                    ah = *(const bf16x8*)(hb_in + (size_t)n_a * DD + ks * 32 + lk * 8);
                } else {
#pragma unroll
                    for (int j = 0; j < 8; ++j) ah[j] = (__bf16)0.f;
                }
            }
            const __bf16* bh_base = wfrag + ((size_t)(pass * 2 + 0) * 4 + ks) * 4096 + lane * 8;
            const __bf16* bl_base = wfrag + ((size_t)(pass * 2 + 1) * 4 + ks) * 4096 + lane * 8;
#pragma unroll
            for (int ct = 0; ct < 8; ++ct) {
                bf16x8 bh = *(const bf16x8*)(bh_base + ct * 512);
                bf16x8 bl = *(const bf16x8*)(bl_base + ct * 512);
                acc[ct] = __builtin_amdgcn_mfma_f32_16x16x32_bf16(ah, bh, acc[ct], 0, 0, 0);
                if (pass == 0)
                    acc[ct] = __builtin_amdgcn_mfma_f32_16x16x32_bf16(al, bh, acc[ct], 0, 0, 0);
                acc[ct] = __builtin_amdgcn_mfma_f32_16x16x32_bf16(ah, bl, acc[ct], 0, 0, 0);
            }
        }
    }

    float cs[8], cq[8];
#pragma unroll
    for (int ct = 0; ct < 8; ++ct) { cs[ct] = 0.f; cq[ct] = 0.f; }
#pragma unroll
    for (int ct = 0; ct < 8; ++ct) {
        int col = ct * 16 + lrow;
        float bt = biast[col];
        float tr = biast[128 + col];
#pragma unroll
        for (int q = 0; q < 4; ++q) {
            int n = r0 + lk * 4 + q;
            if (n < NN) {
                float o = fmaxf(acc[ct][q] + bt + degf[n] * tr, 0.f);
                __bf16 ob = (__bf16)o;
                hb_out[(size_t)n * DD + col] = *(unsigned short*)&ob;
                cs[ct] += o;
                cq[ct] += o * o;
            }
        }
    }
#pragma unroll
    for (int ct = 0; ct < 8; ++ct) {
        cs[ct] += __shfl_xor(cs[ct], 16);
        cs[ct] += __shfl_xor(cs[ct], 32);
        cq[ct] += __shfl_xor(cq[ct], 16);
        cq[ct] += __shfl_xor(cq[ct], 32);
    }
    if (lane < 16) {
#pragma unroll
        for (int ct = 0; ct < 8; ++ct) {
            sb[w][ct * 16 + lrow] = cs[ct];
            qb[w][ct * 16 + lrow] = cq[ct];
        }
    }
    __syncthreads();
    if (tid < 128) {
        float s = sb[0][tid] + sb[1][tid] + sb[2][tid] + sb[3][tid];
        atomicAdd(&stats[tid], s);
    } else {
        int c2 = tid - 128;
        float s = qb[0][c2] + qb[1][c2] + qb[2][c2] + qb[3][c2];
        atomicAdd(&stats[DD + c2], s);
    }
}

// ---------------- pooling stage 1: per-block partials, no global atomics --------

__global__ __launch_bounds__(256) void k_pool(const unsigned short* __restrict__ hb,
                                              const int* __restrict__ batch,
                                              float* __restrict__ pp,   // [PB][NG][DD]
                                              int* __restrict__ pc) {   // [PB][NG]
    __shared__ float sacc[NG][DD];
    __shared__ int scnt[NG];
    const int tid = threadIdx.x;
    const int rs = tid >> 4;     // row stream 0..15
    const int co = tid & 15;     // col octet
#pragma unroll
    for (int j = 0; j < 4; ++j) sacc[(tid * 4 + j) >> 7][(tid * 4 + j) & 127] = 0.f;
    if (tid < NG) scnt[tid] = 0;
    __syncthreads();
    const int chunk = (NN + PB - 1) / PB;
    int lo = blockIdx.x * chunk;
    int hi = lo + chunk; if (hi > NN) hi = NN;
    const uint4* hp = (const uint4*)hb;
    float a[8] = {};
    int cur = -1, cnt = 0;
    for (int n = lo + rs; n < hi; n += 16) {
        int g = batch[n];
        if (g != cur) {
            if (cur >= 0) {
#pragma unroll
                for (int j = 0; j < 8; ++j) atomicAdd(&sacc[cur][co * 8 + j], a[j]);
                if (co == 0) atomicAdd(&scnt[cur], cnt);
#pragma unroll
                for (int j = 0; j < 8; ++j) a[j] = 0.f;
                cnt = 0;
            }
            cur = g;
        }
        uint4 v = hp[(size_t)n * 16 + co];
        a[0] += bflo(v.x); a[1] += bfhi(v.x);
        a[2] += bflo(v.y); a[3] += bfhi(v.y);
        a[4] += bflo(v.z); a[5] += bfhi(v.z);
        a[6] += bflo(v.w); a[7] += bfhi(v.w);
        cnt++;
    }
    if (cur >= 0) {
#pragma unroll
        for (int j = 0; j < 8; ++j) atomicAdd(&sacc[cur][co * 8 + j], a[j]);
        if (co == 0) atomicAdd(&scnt[cur], cnt);
    }
    __syncthreads();
    float* ppb = pp + (size_t)blockIdx.x * NG * DD;
#pragma unroll
    for (int j = 0; j < 4; ++j) {
        int idx = tid * 4 + j;
        ppb[idx] = sacc[idx >> 7][idx & 127];
    }
    if (tid < NG) pc[blockIdx.x * NG + tid] = scnt[tid];
}

// ---------------- head: reduce partials + final BN + dense + mu ----------------

__global__ __launch_bounds__(1024) void k_head(const float* __restrict__ pp,
                                               const int* __restrict__ pc,
                                               const float* __restrict__ statsP,
                                               const float* __restrict__ gammaP,
                                               const float* __restrict__ betaP,
                                               const float* __restrict__ dw,
                                               const float* __restrict__ db,
                                               const float* __restrict__ muw,
                                               const float* __restrict__ mub,
                                               float* __restrict__ out) {
    __shared__ float pm[NG][DD];
    __shared__ float zs[NG][DD];
    int t = threadIdx.x;
    int g = t >> 7, c = t & 127;
    float sum = 0.f;
    for (int b = 0; b < PB; ++b)
        sum += pp[(size_t)b * NG * DD + g * DD + c];
    int cnti = 0;
    for (int b = 0; b < PB; ++b)
        cnti += pc[b * NG + g];
    float cntg = (float)cnti;
    float m = statsP[c] * (1.0f / NN);
    float var = statsP[DD + c] * (1.0f / NN) - m * m;
    float s = gammaP[c] * rsqrtf(var + BN_EPS);
    float tv = betaP[c] - m * s;
    pm[g][c] = fmaf(s, sum, tv * cntg) / fmaxf(cntg, 1.0f);
    __syncthreads();
    float acc = 0.f;
    for (int k = 0; k < DD; ++k)
        acc = fmaf(pm[g][k], dw[k * DD + c], acc);
    float z = fmaxf(acc + db[c], 0.f);
    zs[g][c] = z * muw[c];
    __syncthreads();
    if (c == 0) {
        float s2 = 0.f;
        for (int k = 0; k < DD; ++k) s2 += zs[g][k];
        out[g] = s2 + mub[0];
    }
}

// ---------------- host ----------------

extern "C" void kernel_launch(void* const* d_in, const int* in_sizes, int n_in,
                              void* d_out, int out_size, void* d_ws, size_t ws_size,
                              hipStream_t stream) {
    const float* x      = (const float*)d_in[0];
    const int*   ei     = (const int*)d_in[1];
    const int*   batch  = (const int*)d_in[2];
    const float* W_rel  = (const float*)d_in[3];
    const float* b_rel  = (const float*)d_in[4];
    const float* W_root = (const float*)d_in[5];
    const float* gamma  = (const float*)d_in[6];
    const float* beta   = (const float*)d_in[7];
    const float* dw     = (const float*)d_in[8];
    const float* db     = (const float*)d_in[9];
    const float* muw    = (const float*)d_in[10];
    const float* mub    = (const float*)d_in[11];
    float* out = (float*)d_out;

    char* w = (char*)d_ws;
    auto alloc = [&](size_t bytes) {
        char* p = w;
        w += (bytes + 255) & ~(size_t)255;
        return p;
    };
    int*    off      = (int*)alloc((size_t)(NN + 1) * 4);
    int*    csr      = (int*)alloc((size_t)NE * 4);
    float*  aggb     = (float*)alloc((size_t)NN * DD * 4);  // doubles as partition scratch
    unsigned short* hbA = (unsigned short*)alloc((size_t)NN * DD * 2);
    unsigned short* hbB = (unsigned short*)alloc((size_t)NN * DD * 2);
    float*  degf     = (float*)alloc((size_t)NN * 4);
    float*  statsBuf = (float*)alloc((size_t)NLAYERS * 2 * DD * 4);
    float*  biast    = (float*)alloc(2 * DD * 4);
    float*  pp       = (float*)alloc((size_t)PB * NG * DD * 4);
    int*    pc       = (int*)alloc((size_t)PB * NG * 4);
    int*    bincur   = (int*)alloc(256 * 4);
    int*    binbase  = (int*)alloc(256 * 4);
    __bf16* wfrag    = (__bf16*)alloc((size_t)65536 * 2);   // 128 KB, rewritten per layer

    const int* src = ei;
    const int* dst = ei + NE;
    int2* scratch = (int2*)aggb;  // NBIN*BINCAP*8 = 16.06 MB <= 25.6 MB

    hipMemsetAsync(bincur, 0, 256 * 4, stream);
    hipMemsetAsync(statsBuf, 0, (size_t)NLAYERS * 2 * DD * 4, stream);
    k_part<<<(NE + EPB - 1) / EPB, 1024, 0, stream>>>(src, dst, bincur, scratch);
    k_binscan<<<1, 256, 0, stream>>>(bincur, binbase, off);
    k_csr<<<NBIN, 1024, 0, stream>>>(bincur, binbase, scratch, off, csr, degf);
    k_xtobf<<<(NN * DD / 8 + 255) / 256, 256, 0, stream>>>(x, hbA);

    const unsigned short* hcur = hbA;
    unsigned short* bufs[2] = {hbB, hbA};
    for (int i = 0; i < NLAYERS; ++i) {
        unsigned short* hnext = bufs[i & 1];
        k_prep<<<17, 256, 0, stream>>>(W_rel + (size_t)i * DD * DD,
                                       W_root + (size_t)i * DD * DD,
                                       b_rel + (size_t)i * DD,
                                       gamma + (size_t)(i - 1) * DD,
                                       beta + (size_t)(i - 1) * DD,
                                       statsBuf + (size_t)(i - 1) * 2 * DD,
                                       i == 0 ? 1 : 0, wfrag, biast);
        k_agg<<<(NN * 64 + 255) / 256, 256, 0, stream>>>(hcur, off, csr, aggb);
        k_gemm<<<(NN + 63) / 64, 256, 0, stream>>>(aggb, hcur, wfrag, biast, degf,
                                                   hnext, statsBuf + (size_t)i * 2 * DD);
        hcur = hnext;
    }
    k_pool<<<PB, 256, 0, stream>>>(hcur, batch, pp, pc);
    k_head<<<1, 1024, 0, stream>>>(pp, pc,
                                   statsBuf + (size_t)(NLAYERS - 1) * 2 * DD,
                                   gamma + (size_t)(NLAYERS - 1) * DD,
                                   beta + (size_t)(NLAYERS - 1) * DD,
                                   dw, db, muw, mub, out);
}